// Round 2
// baseline (232.630 us; speedup 1.0000x reference)
//
#include <hip/hip_runtime.h>

// GCN autoencoder: recon = (Z @ Z^T) where
//   h  = X @ W1                      (10000x512 @ 512x32)
//   h1 = relu(spmm(A, h))            (atomic scatter-add over 320k edges)
//   h2 = relu(h1) @ W2
//   z  = spmm(A, h2)
//   out= z @ z^T  (1e8 f32, 400 MB -> HBM-write-bound)
//
// R2 fix: zero h1/h2/z via a KERNEL, not hipMemsetAsync — the memsets did not
// survive graph capture, so replays accumulated atomics into stale h1/z
// (post-timing absmax grew 128 -> 4992). Kernels always capture.

constexpr int N_  = 10000;
constexpr int E_  = 320000;
constexpr int F_  = 512;
constexpr int H1_ = 32;
constexpr int H2_ = 16;

// ---------------- zero workspace (h1, h2, z: contiguous 640k floats) -------
__global__ __launch_bounds__(256) void zero_ws(float4* __restrict__ p, int n4) {
    int i = blockIdx.x * blockDim.x + threadIdx.x;
    if (i < n4) p[i] = make_float4(0.f, 0.f, 0.f, 0.f);
}

// ---------------- h = X @ W1 ----------------
__global__ __launch_bounds__(256) void gemm_xw1(const float* __restrict__ x,
                                                const float* __restrict__ W1,
                                                float* __restrict__ h) {
    int tid = blockIdx.x * blockDim.x + threadIdx.x;
    if (tid >= N_ * H1_) return;
    int r = tid >> 5;          // /32
    int c = tid & (H1_ - 1);
    const float4* xr = reinterpret_cast<const float4*>(x + (size_t)r * F_);
    float acc = 0.f;
#pragma unroll 8
    for (int k4 = 0; k4 < F_ / 4; ++k4) {
        float4 xv = xr[k4];
        int k = k4 * 4;
        acc = fmaf(xv.x, W1[(k + 0) * H1_ + c], acc);
        acc = fmaf(xv.y, W1[(k + 1) * H1_ + c], acc);
        acc = fmaf(xv.z, W1[(k + 2) * H1_ + c], acc);
        acc = fmaf(xv.w, W1[(k + 3) * H1_ + c], acc);
    }
    h[tid] = acc;
}

// ---------------- spmm: out[row[e]] += w[e] * h[col[e]] ----------------
// one thread per (edge, feature); HF consecutive threads share one edge so
// the edge scalars broadcast and the h-row gather / atomic target are
// contiguous HF*4-byte segments. out must be pre-zeroed.
template <int HF>
__global__ __launch_bounds__(256) void spmm_atomic(const float* __restrict__ h,
                                                   const float* __restrict__ ew,
                                                   const int* __restrict__ erow,
                                                   const int* __restrict__ ecol,
                                                   float* __restrict__ out) {
    int tid = blockIdx.x * blockDim.x + threadIdx.x;
    if (tid >= E_ * HF) return;
    int e = tid / HF;
    int f = tid & (HF - 1);
    int r = erow[e];
    int c = ecol[e];
    float v = ew[e] * h[c * HF + f];
    atomicAdd(&out[r * HF + f], v);
}

// ---------------- h2 = relu(h1) @ W2 ----------------
__global__ __launch_bounds__(256) void gemm_h1w2(const float* __restrict__ h1,
                                                 const float* __restrict__ W2,
                                                 float* __restrict__ h2) {
    int tid = blockIdx.x * blockDim.x + threadIdx.x;
    if (tid >= N_ * H2_) return;
    int r = tid >> 4;          // /16
    int c = tid & (H2_ - 1);
    const float* hr = h1 + (size_t)r * H1_;
    float acc = 0.f;
#pragma unroll
    for (int k = 0; k < H1_; ++k)
        acc = fmaf(fmaxf(hr[k], 0.f), W2[k * H2_ + c], acc);
    h2[tid] = acc;
}

// ---------------- out = z @ z^T ----------------
constexpr int BI = 32;
constexpr int BJ = 128;

__global__ __launch_bounds__(256) void zzt(const float* __restrict__ z,
                                           float* __restrict__ out) {
    __shared__ float zi[H2_][BI + 4];
    __shared__ float zj[H2_][BJ + 4];
    const int t  = threadIdx.x;
    const int ib = blockIdx.y * BI;
    const int jb = blockIdx.x * BJ;

    for (int idx = t; idx < BI * H2_; idx += 256) {
        int rl = idx >> 4;
        int k  = idx & 15;
        int gr = ib + rl;
        zi[k][rl] = (gr < N_) ? z[(size_t)gr * H2_ + k] : 0.f;
    }
    for (int idx = t; idx < BJ * H2_; idx += 256) {
        int rl = idx >> 4;
        int k  = idx & 15;
        int gr = jb + rl;
        zj[k][rl] = (gr < N_) ? z[(size_t)gr * H2_ + k] : 0.f;
    }
    __syncthreads();

    const int il = (t >> 5) << 2;   // 0,4,...,28
    const int jl = (t & 31) << 2;   // 0,4,...,124

    float acc[4][4] = {};
#pragma unroll
    for (int k = 0; k < H2_; ++k) {
        float4 a = *reinterpret_cast<const float4*>(&zi[k][il]);
        float4 b = *reinterpret_cast<const float4*>(&zj[k][jl]);
        acc[0][0] = fmaf(a.x, b.x, acc[0][0]);
        acc[0][1] = fmaf(a.x, b.y, acc[0][1]);
        acc[0][2] = fmaf(a.x, b.z, acc[0][2]);
        acc[0][3] = fmaf(a.x, b.w, acc[0][3]);
        acc[1][0] = fmaf(a.y, b.x, acc[1][0]);
        acc[1][1] = fmaf(a.y, b.y, acc[1][1]);
        acc[1][2] = fmaf(a.y, b.z, acc[1][2]);
        acc[1][3] = fmaf(a.y, b.w, acc[1][3]);
        acc[2][0] = fmaf(a.z, b.x, acc[2][0]);
        acc[2][1] = fmaf(a.z, b.y, acc[2][1]);
        acc[2][2] = fmaf(a.z, b.z, acc[2][2]);
        acc[2][3] = fmaf(a.z, b.w, acc[2][3]);
        acc[3][0] = fmaf(a.w, b.x, acc[3][0]);
        acc[3][1] = fmaf(a.w, b.y, acc[3][1]);
        acc[3][2] = fmaf(a.w, b.z, acc[3][2]);
        acc[3][3] = fmaf(a.w, b.w, acc[3][3]);
    }

#pragma unroll
    for (int ii = 0; ii < 4; ++ii) {
        int gi = ib + il + ii;
        if (gi >= N_) continue;
        int gj = jb + jl;
        float* orow = out + (size_t)gi * N_ + gj;
        if (gj + 3 < N_) {
            *reinterpret_cast<float4*>(orow) =
                make_float4(acc[ii][0], acc[ii][1], acc[ii][2], acc[ii][3]);
        } else {
#pragma unroll
            for (int jj = 0; jj < 4; ++jj)
                if (gj + jj < N_) orow[jj] = acc[ii][jj];
        }
    }
}

extern "C" void kernel_launch(void* const* d_in, const int* in_sizes, int n_in,
                              void* d_out, int out_size, void* d_ws, size_t ws_size,
                              hipStream_t stream) {
    const float* x    = (const float*)d_in[0];
    const float* ew   = (const float*)d_in[1];
    const float* W1   = (const float*)d_in[2];
    const float* W2   = (const float*)d_in[3];
    const int*   erow = (const int*)d_in[4];
    const int*   ecol = (const int*)d_in[5];
    float* out = (float*)d_out;

    float* h  = (float*)d_ws;          // N*H1
    float* h1 = h  + N_ * H1_;         // N*H1  (atomic target, zeroed below)
    float* h2 = h1 + N_ * H1_;         // N*H2
    float* z  = h2 + N_ * H2_;         // N*H2  (atomic target, zeroed below)

    // zero h1|h2|z (contiguous 640k floats = 160k float4) via kernel —
    // graph-capture-safe, unlike hipMemsetAsync.
    int n4 = (N_ * H1_ + N_ * H2_ * 2) / 4;
    zero_ws<<<(n4 + 255) / 256, 256, 0, stream>>>((float4*)h1, n4);

    gemm_xw1<<<(N_ * H1_ + 255) / 256, 256, 0, stream>>>(x, W1, h);
    spmm_atomic<H1_><<<(E_ * H1_ + 255) / 256, 256, 0, stream>>>(h, ew, erow, ecol, h1);
    gemm_h1w2<<<(N_ * H2_ + 255) / 256, 256, 0, stream>>>(h1, W2, h2);
    spmm_atomic<H2_><<<(E_ * H2_ + 255) / 256, 256, 0, stream>>>(h2, ew, erow, ecol, z);

    dim3 grid((N_ + BJ - 1) / BJ, (N_ + BI - 1) / BI);
    zzt<<<grid, 256, 0, stream>>>(z, out);
}